// Round 14
// baseline (2107.946 us; speedup 1.0000x reference)
//
#include <hip/hip_runtime.h>

#define D_IN   4096      // D_CONCAT
#define D_HID  16384
#define NTOK   4096      // B*N
#define KSEL   64

// output layout (floats)
#define OUT_ZREC 0
#define OUT_H    ((size_t)NTOK * D_IN)                 // 16,777,216
#define OUT_LAYER (OUT_H + (size_t)NTOK * D_HID)       // 83,886,080

typedef _Float16 f16;
typedef _Float16 f16x4 __attribute__((ext_vector_type(4)));
typedef _Float16 f16x8 __attribute__((ext_vector_type(8)));
typedef float f32x4 __attribute__((ext_vector_type(4)));

#define GLOAD16(gp, lp) __builtin_amdgcn_global_load_lds( \
    (const __attribute__((address_space(1))) void*)(gp),  \
    (__attribute__((address_space(3))) void*)(lp), 16, 0, 0)

// ---------------- fp32 -> (hi,mid) f16 split kernels ----------------
__global__ __launch_bounds__(256) void k_split_a(
    const float* __restrict__ Z, const float* __restrict__ b_dec,
    f16* __restrict__ H, f16* __restrict__ M) {
  size_t i = (size_t)blockIdx.x * 256 + threadIdx.x;     // float4 index
  float4 x = ((const float4*)Z)[i];
  int col = (int)((i * 4) & (D_IN - 1));
  float4 b = *(const float4*)(b_dec + col);
  x.x -= b.x; x.y -= b.y; x.z -= b.z; x.w -= b.w;
  f16 h0 = (f16)x.x, h1 = (f16)x.y, h2 = (f16)x.z, h3 = (f16)x.w;
  f16 m0 = (f16)(x.x - (float)h0), m1 = (f16)(x.y - (float)h1);
  f16 m2 = (f16)(x.z - (float)h2), m3 = (f16)(x.w - (float)h3);
  f16x4 hv = {h0, h1, h2, h3}, mv = {m0, m1, m2, m3};
  ((f16x4*)H)[i] = hv;
  ((f16x4*)M)[i] = mv;
}

__global__ __launch_bounds__(256) void k_split_w(
    const float* __restrict__ W, f16* __restrict__ H, f16* __restrict__ M) {
  size_t i = (size_t)blockIdx.x * 256 + threadIdx.x;     // float4 index
  float4 x = ((const float4*)W)[i];
  f16 h0 = (f16)x.x, h1 = (f16)x.y, h2 = (f16)x.z, h3 = (f16)x.w;
  f16 m0 = (f16)(x.x - (float)h0), m1 = (f16)(x.y - (float)h1);
  f16 m2 = (f16)(x.z - (float)h2), m3 = (f16)(x.w - (float)h3);
  f16x4 hv = {h0, h1, h2, h3}, mv = {m0, m1, m2, m3};
  ((f16x4*)H)[i] = hv;
  ((f16x4*)M)[i] = mv;
}

// ---------------- split-f16 MFMA GEMM: pre = A @ W^T + b_enc ----------------
// 256x256 tile, BK=32, 8 waves (2M x 4N), 128 KiB LDS double-buffer.
// MFMA shape: 16x16x32 ONLY. *** NUMERICS FROZEN (R9 lesson): per acc, K runs
// in 128 sequential BK=32 tiles, each adding hh -> hm -> mh with K=32-per-MFMA
// internal grouping. Scheduling/mapping changes only. ***
// *** R12 lesson (rule #20): acc must be STATICALLY indexed. R14's stagger uses
// a wave-uniform branch over two fully-unrolled static bodies (JBLOCK macro with
// literal j) — no runtime acc index, no scratch. ***
// LDS row = 128 B = 8 slots of 16 B; physical slot = g ^ (row & 7)  (T2 swizzle,
// pre-swizzled global source + swizzled ds_read; 0 conflicts, verified).
// Block mapping: bn-OUTER (L3-shared W window; R11: FETCH 2.1->1.6GB, +7% util).
// R14: (a) all 8 prefetch loads issued at tile TOP (last load gets ~full MFMA
// phase of cover before the trailing vmcnt(0)); (b) SIMD-paired waves run the
// j-quadrants rotated by 2 (w>>2 branch) so their W-fragment ds_reads/MFMA
// clusters interleave instead of colliding.
#define BM 256
#define BN 256
#define BK 32
#define NT (D_IN / BK)   // 128

__global__ __launch_bounds__(512, 2) void k_gemm3(
    const f16* __restrict__ Ahg, const f16* __restrict__ Amg,
    const f16* __restrict__ Whg, const f16* __restrict__ Wmg,
    const float* __restrict__ b_enc, float* __restrict__ P) {
  __shared__ __align__(16) char smem[131072];   // 2 buffers x 64 KiB
  const int tid = threadIdx.x;
  const int lane = tid & 63, w = tid >> 6;

  const int bm = blockIdx.x & 15, bn = blockIdx.x >> 4;   // bn-outer (L3-shared W window)
  const int row0 = bm * BM, col0 = bn * BN;
  const int wr = w >> 2, wc = w & 3;     // 2 x 4 waves; wave tile 128 x 64
  const bool jswap = ((w >> 2) & 1);     // SIMD-paired waves offset by 2 quadrants

  const char* gp[8];
  int ldst[8];
#pragma unroll
  for (int j = 0; j < 8; j++) {
    int id = tid + j * 512;
    bool isA = (j < 4);
    int r = isA ? (id >> 3) : ((id >> 3) - 256);   // 0..255
    int ps = id & 7;
    int g = ps ^ (r & 7);
    int plane = g >> 2, kc = g & 3;
    const f16* base = isA ? (plane ? Amg : Ahg) : (plane ? Wmg : Whg);
    int rg = (isA ? row0 : col0) + r;
    gp[j] = (const char*)base + (size_t)rg * 8192 + kc * 16;
    ldst[j] = id * 16;                              // A: [0,32K), W: [32K,64K)
  }

  f32x4 acc[8][4] = {};
  const int l15 = lane & 15;
  const int physh = ((lane >> 4) ^ (lane & 7)) * 16;  // hi-plane slot byte
  const int physm = physh ^ 64;                       // mid-plane slot byte
  const int arow0 = wr * 128 + l15;
  const int wrow0 = wc * 64 + l15;

  // prologue: stage tile 0, publish
#pragma unroll
  for (int j = 0; j < 8; j++) { GLOAD16(gp[j], smem + ldst[j]); gp[j] += 64; }
  asm volatile("s_waitcnt vmcnt(0)" ::: "memory");
  __builtin_amdgcn_s_barrier();

#define JBLOCK(J)                                                                        \
  do {                                                                                   \
    int ro = (wrow0 + (J) * 16) * 128;                                                   \
    f16x8 wh = *(const f16x8*)(Wb + ro + physh);                                         \
    f16x8 wm = *(const f16x8*)(Wb + ro + physm);                                         \
    _Pragma("unroll")                                                                    \
    for (int i = 0; i < 8; i++)                                                          \
      acc[i][J] = __builtin_amdgcn_mfma_f32_16x16x32_f16(ah[i], wh, acc[i][J], 0, 0, 0); \
    _Pragma("unroll")                                                                    \
    for (int i = 0; i < 8; i++)                                                          \
      acc[i][J] = __builtin_amdgcn_mfma_f32_16x16x32_f16(ah[i], wm, acc[i][J], 0, 0, 0); \
    _Pragma("unroll")                                                                    \
    for (int i = 0; i < 8; i++)                                                          \
      acc[i][J] = __builtin_amdgcn_mfma_f32_16x16x32_f16(am[i], wh, acc[i][J], 0, 0, 0); \
  } while (0)

  for (int t = 0; t < NT; t++) {
    const char* Ab = smem + (t & 1) * 65536;
    const char* Wb = Ab + 32768;
    const int nb = ((t + 1) & 1) * 65536;

    // burst-issue ALL next-tile loads at tile top: last load gets ~full-body cover
    if (t + 1 < NT) {
#pragma unroll
      for (int j = 0; j < 8; j++) { GLOAD16(gp[j], smem + nb + ldst[j]); gp[j] += 64; }
    }

    f16x8 ah[8], am[8];
#pragma unroll
    for (int i = 0; i < 8; i++) {
      int ro = (arow0 + i * 16) * 128;
      ah[i] = *(const f16x8*)(Ab + ro + physh);
      am[i] = *(const f16x8*)(Ab + ro + physm);
    }
    __builtin_amdgcn_s_setprio(1);
    if (jswap) { JBLOCK(2); JBLOCK(3); JBLOCK(0); JBLOCK(1); }
    else       { JBLOCK(0); JBLOCK(1); JBLOCK(2); JBLOCK(3); }
    __builtin_amdgcn_s_setprio(0);
    asm volatile("s_waitcnt vmcnt(0)" ::: "memory");   // next-tile loads landed
    __builtin_amdgcn_sched_barrier(0);
    __builtin_amdgcn_s_barrier();
    __builtin_amdgcn_sched_barrier(0);
  }
#undef JBLOCK

  // epilogue: C/D layout col=lane&15, row=(lane>>4)*4+q (m89-verified)
  const int crow0 = row0 + wr * 128, ccol0 = col0 + wc * 64;
#pragma unroll
  for (int j = 0; j < 4; j++) {
    int col = ccol0 + j * 16 + l15;
    float be = b_enc[col];
#pragma unroll
    for (int i = 0; i < 8; i++) {
      int r = crow0 + i * 16 + ((lane >> 4) * 4);
#pragma unroll
      for (int q = 0; q < 4; q++)
        __builtin_nontemporal_store(acc[i][j][q] + be, P + (size_t)(r + q) * D_HID + col);
    }
  }
}

// ---------------- legacy fp32 GEMM (fallback when ws is too small) ----------------
#define FBM 128
#define FBN 128
#define FBK 32
__global__ __launch_bounds__(256) void k_gemm_enc(
    const float* __restrict__ Z, const float* __restrict__ W,
    const float* __restrict__ b_enc, const float* __restrict__ b_dec,
    float* __restrict__ P) {
  __shared__ float As[FBK][FBM + 4];
  __shared__ float Bs[FBK][FBN + 4];
  const int tid = threadIdx.x;
  const int bm = blockIdx.y, bn = blockIdx.x;
  const int ty = tid >> 4, tx = tid & 15;
  const int row0 = bm * FBM, col0 = bn * FBN;
  float acc[8][8];
#pragma unroll
  for (int i = 0; i < 8; i++)
#pragma unroll
    for (int j = 0; j < 8; j++) acc[i][j] = 0.f;
  for (int k0 = 0; k0 < D_IN; k0 += FBK) {
#pragma unroll
    for (int i = 0; i < 4; i++) {
      int f = tid + i * 256;
      int r = f >> 3;
      int c = (f & 7) * 4;
      float4 bd = *(const float4*)(b_dec + k0 + c);
      float4 a = *(const float4*)(Z + (size_t)(row0 + r) * D_IN + k0 + c);
      float4 w = *(const float4*)(W + (size_t)(col0 + r) * D_IN + k0 + c);
      As[c + 0][r] = a.x - bd.x; As[c + 1][r] = a.y - bd.y;
      As[c + 2][r] = a.z - bd.z; As[c + 3][r] = a.w - bd.w;
      Bs[c + 0][r] = w.x; Bs[c + 1][r] = w.y;
      Bs[c + 2][r] = w.z; Bs[c + 3][r] = w.w;
    }
    __syncthreads();
#pragma unroll
    for (int kk = 0; kk < FBK; kk++) {
      const float4* ap = (const float4*)&As[kk][ty * 8];
      const float4* bp = (const float4*)&Bs[kk][tx * 8];
      float4 a0 = ap[0], a1 = ap[1], b0 = bp[0], b1 = bp[1];
      float a[8] = {a0.x, a0.y, a0.z, a0.w, a1.x, a1.y, a1.z, a1.w};
      float b[8] = {b0.x, b0.y, b0.z, b0.w, b1.x, b1.y, b1.z, b1.w};
#pragma unroll
      for (int i = 0; i < 8; i++)
#pragma unroll
        for (int j = 0; j < 8; j++) acc[i][j] += a[i] * b[j];
    }
    __syncthreads();
  }
  float4 be0 = *(const float4*)(b_enc + col0 + tx * 8);
  float4 be1 = *(const float4*)(b_enc + col0 + tx * 8 + 4);
#pragma unroll
  for (int i = 0; i < 8; i++) {
    size_t o = (size_t)(row0 + ty * 8 + i) * D_HID + col0 + tx * 8;
    float4 o0 = {acc[i][0] + be0.x, acc[i][1] + be0.y, acc[i][2] + be0.z, acc[i][3] + be0.w};
    float4 o1 = {acc[i][4] + be1.x, acc[i][5] + be1.y, acc[i][6] + be1.z, acc[i][7] + be1.w};
    *(float4*)(P + o) = o0;
    *(float4*)(P + o + 4) = o1;
  }
}

// ---------------- TopK: exact radix-select, conflict-free, atomic-light ----------
#define SCAN256()                                            \
  do {                                                       \
    for (int off = 1; off < 256; off <<= 1) {                \
      unsigned v = scan[tid];                                \
      unsigned a = (tid >= off) ? scan[tid - off] : 0u;      \
      __syncthreads();                                       \
      scan[tid] = v + a;                                     \
      __syncthreads();                                       \
    }                                                        \
  } while (0)

__global__ __launch_bounds__(256) void k_topk(
    float* __restrict__ H, float* __restrict__ sel_v, int* __restrict__ sel_i) {
  __shared__ float row[D_HID];          // 64KB
  __shared__ unsigned hist[4][256];     // per-wave replicas
  __shared__ unsigned scan[256];
  __shared__ unsigned sh_prefix, sh_cntgt;
  __shared__ int eqbuf[256];
  __shared__ unsigned eqn, keepn;
  __shared__ int sh_eqcut;
  const int tid = threadIdx.x;
  const size_t t = blockIdx.x;
  float* rowg = H + t * D_HID;

  for (int i = tid; i < D_HID / 4; i += 256) {
    float4 v = ((const float4*)rowg)[i];
    v.x = v.x > 0.f ? v.x : 0.f;
    v.y = v.y > 0.f ? v.y : 0.f;
    v.z = v.z > 0.f ? v.z : 0.f;
    v.w = v.w > 0.f ? v.w : 0.f;
    ((float4*)row)[i] = v;
  }
  if (tid == 0) { sh_prefix = 0; sh_cntgt = 0; eqn = 0; keepn = 0; }
  __syncthreads();

  const f32x4* row4 = (const f32x4*)row;
  for (int p = 3; p >= 0; p--) {
    hist[0][tid] = 0; hist[1][tid] = 0; hist[2][tid] = 0; hist[3][tid] = 0;
    __syncthreads();
    const unsigned prefix = sh_prefix;
    const unsigned need = KSEL - sh_cntgt;
    const unsigned hi_mask = (p == 3) ? 0u : (0xFFFFFFFFu << (8 * (p + 1)));
    const int sh = 8 * p;
    unsigned* hrep = hist[tid >> 6];
    for (int j = 0; j < D_HID / 1024; j++) {       // 16 x f32x4 per thread
      f32x4 v = row4[j * 256 + tid];
#pragma unroll
      for (int e = 0; e < 4; e++) {
        unsigned bits = __float_as_uint(v[e]);
        if (bits && ((bits ^ prefix) & hi_mask) == 0)
          atomicAdd(&hrep[(bits >> sh) & 255], 1u);
      }
    }
    __syncthreads();
    scan[tid] = hist[0][255 - tid] + hist[1][255 - tid] + hist[2][255 - tid] + hist[3][255 - tid];
    __syncthreads();
    SCAN256();
    unsigned Sb  = scan[255 - tid];
    unsigned Sb1 = (tid == 255) ? 0u : scan[254 - tid];
    if (Sb >= need && Sb1 < need) {
      sh_prefix = prefix | ((unsigned)tid << sh);
      sh_cntgt = (KSEL - need) + Sb1;
    }
    if (tid == 0 && scan[255] < need) {        // degenerate: zeros needed -> bin 0
      sh_prefix = prefix;
      sh_cntgt = (KSEL - need) + scan[255];
    }
    __syncthreads();
  }
  const unsigned thr = sh_prefix;
  const unsigned need_eq = KSEL - sh_cntgt;   // in [1, 64]

  // Phase A: find eqcut = need_eq-th smallest index with bits == thr.
  for (int j = 0; j < D_HID / 256; j++) {
    int idx = j * 256 + tid;
    if (__float_as_uint(row[idx]) == thr) {
      unsigned p = atomicAdd(&eqn, 1u);
      if (p < 256) eqbuf[p] = idx;
    }
  }
  __syncthreads();
  const unsigned en = eqn;
  if (en <= 256) {
    if (tid < en) {
      int mine = eqbuf[tid];
      unsigned rank = 0;
      for (unsigned j = 0; j < en; j++) rank += (eqbuf[j] < mine) ? 1u : 0u;
      if (rank == need_eq - 1) sh_eqcut = mine;
    }
    __syncthreads();
  } else {
    int lo = 0, hi = D_HID - 1;
    while (lo < hi) {
      int mid = (lo + hi) >> 1;
      if (tid == 0) scan[0] = 0;
      __syncthreads();
      unsigned c = 0;
      for (int j = 0; j < D_HID / 256; j++) {
        int idx = j * 256 + tid;
        if (idx <= mid && __float_as_uint(row[idx]) == thr) c++;
      }
      atomicAdd(&scan[0], c);
      __syncthreads();
      if (scan[0] >= need_eq) hi = mid; else lo = mid + 1;
      __syncthreads();
    }
    if (tid == 0) sh_eqcut = lo;
    __syncthreads();
  }
  const int eqcut = sh_eqcut;

  // Phase B+C merged: mask + write sparse row; append kept (idx,val) to sel
  for (int i = tid; i < D_HID / 4; i += 256) {
    f32x4 v = ((const f32x4*)row)[i];
    int i0 = i * 4;
#pragma unroll
    for (int e = 0; e < 4; e++) {
      unsigned b = __float_as_uint(v[e]);
      bool keep = (b > thr) || (b == thr && i0 + e <= eqcut);
      if (keep) {
        unsigned p = atomicAdd(&keepn, 1u);
        sel_v[t * KSEL + p] = v[e];
        sel_i[t * KSEL + p] = i0 + e;
      } else {
        v[e] = 0.f;
      }
    }
    __builtin_nontemporal_store(v, (f32x4*)rowg + i);
  }
}

// ---------------- W_dec transpose -> f16 (64x64 tile, 128-B write segments) ------
__global__ __launch_bounds__(256) void k_transpose(const float* __restrict__ in,
                                                   f16* __restrict__ out) {
  __shared__ float tile[64][65];
  const int bx = blockIdx.x;   // h tiles (D_HID/64)
  const int by = blockIdx.y;   // d tiles (D_IN/64)
  const int tid = threadIdx.x;
#pragma unroll
  for (int p = 0; p < 16; p++) {
    int lin = p * 256 + tid;
    int dr = lin >> 6;          // d offset 0..63
    int dc = lin & 63;          // h offset 0..63
    tile[dc][dr] = in[(size_t)(by * 64 + dr) * D_HID + bx * 64 + dc];
  }
  __syncthreads();
#pragma unroll
  for (int p = 0; p < 16; p++) {
    int lin = p * 256 + tid;
    int h = lin >> 6;           // h offset 0..63
    int d = lin & 63;           // d offset 0..63
    out[(size_t)(bx * 64 + h) * D_IN + by * 64 + d] = (f16)tile[h][d];
  }
}

// ---------------- Decoder: z_rec[t,:] = sum_k val_k * WdT[idx_k,:] + b_dec -------
__global__ __launch_bounds__(512) void k_decode(
    const float* __restrict__ sel_v, const int* __restrict__ sel_i,
    const f16* __restrict__ WdT, const float* __restrict__ b_dec,
    float* __restrict__ out) {
  const int tid = threadIdx.x;
  const size_t t = blockIdx.x;
  __shared__ float sv[KSEL];
  __shared__ int si[KSEL];
  if (tid < KSEL) { sv[tid] = sel_v[t * KSEL + tid]; si[tid] = sel_i[t * KSEL + tid]; }
  __syncthreads();
  float acc[8];
#pragma unroll
  for (int e = 0; e < 8; e++) acc[e] = b_dec[tid * 8 + e];
#pragma unroll 8
  for (int k = 0; k < KSEL; k++) {
    float v = sv[k];
    f16x8 w = ((const f16x8*)(WdT + (size_t)si[k] * D_IN))[tid];
#pragma unroll
    for (int e = 0; e < 8; e++) acc[e] += v * (float)w[e];
  }
  const int d0 = tid * 8;
  f32x4 o0 = {acc[0], acc[1], acc[2], acc[3]};
  f32x4 o1 = {acc[4], acc[5], acc[6], acc[7]};
  __builtin_nontemporal_store(o0, (f32x4*)(out + t * D_IN + d0));
  __builtin_nontemporal_store(o1, (f32x4*)(out + t * D_IN + d0 + 4));
  int l = d0 >> 10, off = d0 & 1023;
  float* lp = out + OUT_LAYER + ((size_t)l * NTOK + t) * 1024 + off;
  __builtin_nontemporal_store(o0, (f32x4*)lp);
  __builtin_nontemporal_store(o1, (f32x4*)(lp + 4));
}

// Fallback decoder without transposed W_dec (slow but correct)
__global__ __launch_bounds__(256) void k_decode_slow(
    const float* __restrict__ sel_v, const int* __restrict__ sel_i,
    const float* __restrict__ Wd, const float* __restrict__ b_dec,
    float* __restrict__ out) {
  const int tid = threadIdx.x;
  const size_t t = blockIdx.x;
  __shared__ float sv[KSEL];
  __shared__ int si[KSEL];
  if (tid < KSEL) { sv[tid] = sel_v[t * KSEL + tid]; si[tid] = sel_i[t * KSEL + tid]; }
  __syncthreads();
  float acc[16];
#pragma unroll
  for (int i = 0; i < 16; i++) acc[i] = b_dec[i * 256 + tid];
  for (int k = 0; k < KSEL; k++) {
    float v = sv[k];
    int idx = si[k];
#pragma unroll
    for (int i = 0; i < 16; i++)
      acc[i] += v * Wd[(size_t)(i * 256 + tid) * D_HID + idx];
  }
  for (int i = 0; i < 16; i++) {
    int d = i * 256 + tid;
    out[t * D_IN + d] = acc[i];
    int l = d >> 10, off = d & 1023;
    out[OUT_LAYER + (size_t)l * NTOK * 1024 + t * 1024 + off] = acc[i];
  }
}

extern "C" void kernel_launch(void* const* d_in, const int* in_sizes, int n_in,
                              void* d_out, int out_size, void* d_ws, size_t ws_size,
                              hipStream_t stream) {
  const float* z     = (const float*)d_in[0];
  const float* W_enc = (const float*)d_in[1];
  const float* b_enc = (const float*)d_in[2];
  const float* W_dec = (const float*)d_in[3];
  const float* b_dec = (const float*)d_in[4];
  float* out = (float*)d_out;
  float* pre = out + OUT_H;  // pre-activations live in the h_sparse output slot

  float* sel_v = (float*)d_ws;                              // 1 MiB
  int*   sel_i = (int*)((char*)d_ws + (1u << 20));          // 1 MiB
  char*  wsbig = (char*)d_ws + (2u << 20);                  // 256 MiB region
  const size_t need_ws = (size_t)(2u << 20) + (size_t)D_HID * D_IN * 4;
  const bool fast = ws_size >= need_ws;

  if (fast) {
    // A planes in the z_rec output region (dead until decode); W planes in the
    // ws region later overwritten by WdT (dead after GEMM).
    f16* Ahp = (f16*)out;                         // 32 MiB
    f16* Amp = Ahp + (size_t)NTOK * D_IN;         // 32 MiB
    f16* Whp = (f16*)wsbig;                       // 128 MiB
    f16* Wmp = Whp + (size_t)D_HID * D_IN;        // 128 MiB
    f16* WdT = (f16*)wsbig;                       // f16, reuses W-plane region after GEMM

    k_split_a<<<NTOK * D_IN / 1024, 256, 0, stream>>>(z, b_dec, Ahp, Amp);
    k_split_w<<<D_HID * D_IN / 1024, 256, 0, stream>>>(W_enc, Whp, Wmp);
    k_gemm3<<<(NTOK / BM) * (D_HID / BN), 512, 0, stream>>>(Ahp, Amp, Whp, Wmp, b_enc, pre);
    k_topk<<<NTOK, 256, 0, stream>>>(pre, sel_v, sel_i);
    k_transpose<<<dim3(D_HID / 64, D_IN / 64), 256, 0, stream>>>(W_dec, WdT);
    k_decode<<<NTOK, 512, 0, stream>>>(sel_v, sel_i, WdT, b_dec, out);
  } else {
    dim3 gb(D_HID / FBN, NTOK / FBM);
    k_gemm_enc<<<gb, 256, 0, stream>>>(z, W_enc, b_enc, b_dec, pre);
    k_topk<<<NTOK, 256, 0, stream>>>(pre, sel_v, sel_i);
    k_decode_slow<<<NTOK, 256, 0, stream>>>(sel_v, sel_i, W_dec, b_dec, out);
  }
}

// Round 15
// 1998.453 us; speedup vs baseline: 1.0548x; 1.0548x over previous
//
#include <hip/hip_runtime.h>

#define D_IN   4096      // D_CONCAT
#define D_HID  16384
#define NTOK   4096      // B*N
#define KSEL   64

// output layout (floats)
#define OUT_ZREC 0
#define OUT_H    ((size_t)NTOK * D_IN)                 // 16,777,216
#define OUT_LAYER (OUT_H + (size_t)NTOK * D_HID)       // 83,886,080

typedef _Float16 f16;
typedef _Float16 f16x4 __attribute__((ext_vector_type(4)));
typedef _Float16 f16x8 __attribute__((ext_vector_type(8)));
typedef float f32x4 __attribute__((ext_vector_type(4)));

#define GLOAD16(gp, lp) __builtin_amdgcn_global_load_lds( \
    (const __attribute__((address_space(1))) void*)(gp),  \
    (__attribute__((address_space(3))) void*)(lp), 16, 0, 0)

// ---------------- fp32 -> (hi,mid) f16 split kernels ----------------
__global__ __launch_bounds__(256) void k_split_a(
    const float* __restrict__ Z, const float* __restrict__ b_dec,
    f16* __restrict__ H, f16* __restrict__ M) {
  size_t i = (size_t)blockIdx.x * 256 + threadIdx.x;     // float4 index
  float4 x = ((const float4*)Z)[i];
  int col = (int)((i * 4) & (D_IN - 1));
  float4 b = *(const float4*)(b_dec + col);
  x.x -= b.x; x.y -= b.y; x.z -= b.z; x.w -= b.w;
  f16 h0 = (f16)x.x, h1 = (f16)x.y, h2 = (f16)x.z, h3 = (f16)x.w;
  f16 m0 = (f16)(x.x - (float)h0), m1 = (f16)(x.y - (float)h1);
  f16 m2 = (f16)(x.z - (float)h2), m3 = (f16)(x.w - (float)h3);
  f16x4 hv = {h0, h1, h2, h3}, mv = {m0, m1, m2, m3};
  ((f16x4*)H)[i] = hv;
  ((f16x4*)M)[i] = mv;
}

__global__ __launch_bounds__(256) void k_split_w(
    const float* __restrict__ W, f16* __restrict__ H, f16* __restrict__ M) {
  size_t i = (size_t)blockIdx.x * 256 + threadIdx.x;     // float4 index
  float4 x = ((const float4*)W)[i];
  f16 h0 = (f16)x.x, h1 = (f16)x.y, h2 = (f16)x.z, h3 = (f16)x.w;
  f16 m0 = (f16)(x.x - (float)h0), m1 = (f16)(x.y - (float)h1);
  f16 m2 = (f16)(x.z - (float)h2), m3 = (f16)(x.w - (float)h3);
  f16x4 hv = {h0, h1, h2, h3}, mv = {m0, m1, m2, m3};
  ((f16x4*)H)[i] = hv;
  ((f16x4*)M)[i] = mv;
}

// ---------------- split-f16 MFMA GEMM: pre = A @ W^T + b_enc ----------------
// 256x256 tile, BK=32, 8 waves (2M x 4N), 128 KiB LDS double-buffer.
// MFMA shape: 16x16x32 ONLY. *** NUMERICS FROZEN (R9 lesson): per acc, K runs
// in 128 sequential BK=32 tiles, each adding hh -> hm -> mh with K=32-per-MFMA
// internal grouping. Scheduling/mapping changes only. ***
// *** R12 lesson (rule #20): acc must be STATICALLY indexed (runtime j ->
// scratch spill, 7x). R14 lesson: duplicated unrolled MFMA bodies (jswap
// branch) overflow the 128-VGPR budget -> partial spill (WRITE_SIZE 2x);
// burst-staging at tile top re-creates the issue clump. This is the R13
// configuration — the verified local optimum of the 2-barrier structure. ***
// LDS row = 128 B = 8 slots of 16 B; physical slot = g ^ (row & 7)  (T2 swizzle,
// pre-swizzled global source + swizzled ds_read; 0 conflicts, verified).
// Block mapping: bn-OUTER (L3-shared W window; R11: FETCH 2.1->1.6GB, +7% util).
#define BM 256
#define BN 256
#define BK 32
#define NT (D_IN / BK)   // 128

__global__ __launch_bounds__(512, 2) void k_gemm3(
    const f16* __restrict__ Ahg, const f16* __restrict__ Amg,
    const f16* __restrict__ Whg, const f16* __restrict__ Wmg,
    const float* __restrict__ b_enc, float* __restrict__ P) {
  __shared__ __align__(16) char smem[131072];   // 2 buffers x 64 KiB
  const int tid = threadIdx.x;
  const int lane = tid & 63, w = tid >> 6;

  const int bm = blockIdx.x & 15, bn = blockIdx.x >> 4;   // bn-outer (L3-shared W window)
  const int row0 = bm * BM, col0 = bn * BN;
  const int wr = w >> 2, wc = w & 3;     // 2 x 4 waves; wave tile 128 x 64

  const char* gp[8];
  int ldst[8];
#pragma unroll
  for (int j = 0; j < 8; j++) {
    int id = tid + j * 512;
    bool isA = (j < 4);
    int r = isA ? (id >> 3) : ((id >> 3) - 256);   // 0..255
    int ps = id & 7;
    int g = ps ^ (r & 7);
    int plane = g >> 2, kc = g & 3;
    const f16* base = isA ? (plane ? Amg : Ahg) : (plane ? Wmg : Whg);
    int rg = (isA ? row0 : col0) + r;
    gp[j] = (const char*)base + (size_t)rg * 8192 + kc * 16;
    ldst[j] = id * 16;                              // A: [0,32K), W: [32K,64K)
  }

  f32x4 acc[8][4] = {};
  const int l15 = lane & 15;
  const int physh = ((lane >> 4) ^ (lane & 7)) * 16;  // hi-plane slot byte
  const int physm = physh ^ 64;                       // mid-plane slot byte
  const int arow0 = wr * 128 + l15;
  const int wrow0 = wc * 64 + l15;

  // prologue: stage tile 0, publish
#pragma unroll
  for (int j = 0; j < 8; j++) { GLOAD16(gp[j], smem + ldst[j]); gp[j] += 64; }
  asm volatile("s_waitcnt vmcnt(0)" ::: "memory");
  __builtin_amdgcn_s_barrier();

  for (int t = 0; t < NT; t++) {
    const char* Ab = smem + (t & 1) * 65536;
    const char* Wb = Ab + 32768;
    const int nb = ((t + 1) & 1) * 65536;
    const bool pre = (t + 1 < NT);

    // stage pair 0 early; pairs 1..3 spread over the j-loop
    if (pre) {
      GLOAD16(gp[0], smem + nb + ldst[0]); gp[0] += 64;
      GLOAD16(gp[4], smem + nb + ldst[4]); gp[4] += 64;
    }

    f16x8 ah[8], am[8];
#pragma unroll
    for (int i = 0; i < 8; i++) {
      int ro = (arow0 + i * 16) * 128;
      ah[i] = *(const f16x8*)(Ab + ro + physh);
      am[i] = *(const f16x8*)(Ab + ro + physm);
    }
    __builtin_amdgcn_s_setprio(1);
#pragma unroll
    for (int j = 0; j < 4; j++) {
      if (j >= 1 && pre) {
        GLOAD16(gp[j],     smem + nb + ldst[j]);     gp[j] += 64;
        GLOAD16(gp[4 + j], smem + nb + ldst[4 + j]); gp[4 + j] += 64;
      }
      int ro = (wrow0 + j * 16) * 128;
      f16x8 wh = *(const f16x8*)(Wb + ro + physh);
      f16x8 wm = *(const f16x8*)(Wb + ro + physm);
#pragma unroll
      for (int i = 0; i < 8; i++)
        acc[i][j] = __builtin_amdgcn_mfma_f32_16x16x32_f16(ah[i], wh, acc[i][j], 0, 0, 0);
#pragma unroll
      for (int i = 0; i < 8; i++)
        acc[i][j] = __builtin_amdgcn_mfma_f32_16x16x32_f16(ah[i], wm, acc[i][j], 0, 0, 0);
#pragma unroll
      for (int i = 0; i < 8; i++)
        acc[i][j] = __builtin_amdgcn_mfma_f32_16x16x32_f16(am[i], wh, acc[i][j], 0, 0, 0);
    }
    __builtin_amdgcn_s_setprio(0);
    asm volatile("s_waitcnt vmcnt(0)" ::: "memory");   // tile t+1 landed (issued 1 body ago)
    __builtin_amdgcn_sched_barrier(0);
    __builtin_amdgcn_s_barrier();
    __builtin_amdgcn_sched_barrier(0);
  }

  // epilogue: C/D layout col=lane&15, row=(lane>>4)*4+q (m89-verified)
  const int crow0 = row0 + wr * 128, ccol0 = col0 + wc * 64;
#pragma unroll
  for (int j = 0; j < 4; j++) {
    int col = ccol0 + j * 16 + l15;
    float be = b_enc[col];
#pragma unroll
    for (int i = 0; i < 8; i++) {
      int r = crow0 + i * 16 + ((lane >> 4) * 4);
#pragma unroll
      for (int q = 0; q < 4; q++)
        __builtin_nontemporal_store(acc[i][j][q] + be, P + (size_t)(r + q) * D_HID + col);
    }
  }
}

// ---------------- legacy fp32 GEMM (fallback when ws is too small) ----------------
#define FBM 128
#define FBN 128
#define FBK 32
__global__ __launch_bounds__(256) void k_gemm_enc(
    const float* __restrict__ Z, const float* __restrict__ W,
    const float* __restrict__ b_enc, const float* __restrict__ b_dec,
    float* __restrict__ P) {
  __shared__ float As[FBK][FBM + 4];
  __shared__ float Bs[FBK][FBN + 4];
  const int tid = threadIdx.x;
  const int bm = blockIdx.y, bn = blockIdx.x;
  const int ty = tid >> 4, tx = tid & 15;
  const int row0 = bm * FBM, col0 = bn * FBN;
  float acc[8][8];
#pragma unroll
  for (int i = 0; i < 8; i++)
#pragma unroll
    for (int j = 0; j < 8; j++) acc[i][j] = 0.f;
  for (int k0 = 0; k0 < D_IN; k0 += FBK) {
#pragma unroll
    for (int i = 0; i < 4; i++) {
      int f = tid + i * 256;
      int r = f >> 3;
      int c = (f & 7) * 4;
      float4 bd = *(const float4*)(b_dec + k0 + c);
      float4 a = *(const float4*)(Z + (size_t)(row0 + r) * D_IN + k0 + c);
      float4 w = *(const float4*)(W + (size_t)(col0 + r) * D_IN + k0 + c);
      As[c + 0][r] = a.x - bd.x; As[c + 1][r] = a.y - bd.y;
      As[c + 2][r] = a.z - bd.z; As[c + 3][r] = a.w - bd.w;
      Bs[c + 0][r] = w.x; Bs[c + 1][r] = w.y;
      Bs[c + 2][r] = w.z; Bs[c + 3][r] = w.w;
    }
    __syncthreads();
#pragma unroll
    for (int kk = 0; kk < FBK; kk++) {
      const float4* ap = (const float4*)&As[kk][ty * 8];
      const float4* bp = (const float4*)&Bs[kk][tx * 8];
      float4 a0 = ap[0], a1 = ap[1], b0 = bp[0], b1 = bp[1];
      float a[8] = {a0.x, a0.y, a0.z, a0.w, a1.x, a1.y, a1.z, a1.w};
      float b[8] = {b0.x, b0.y, b0.z, b0.w, b1.x, b1.y, b1.z, b1.w};
#pragma unroll
      for (int i = 0; i < 8; i++)
#pragma unroll
        for (int j = 0; j < 8; j++) acc[i][j] += a[i] * b[j];
    }
    __syncthreads();
  }
  float4 be0 = *(const float4*)(b_enc + col0 + tx * 8);
  float4 be1 = *(const float4*)(b_enc + col0 + tx * 8 + 4);
#pragma unroll
  for (int i = 0; i < 8; i++) {
    size_t o = (size_t)(row0 + ty * 8 + i) * D_HID + col0 + tx * 8;
    float4 o0 = {acc[i][0] + be0.x, acc[i][1] + be0.y, acc[i][2] + be0.z, acc[i][3] + be0.w};
    float4 o1 = {acc[i][4] + be1.x, acc[i][5] + be1.y, acc[i][6] + be1.z, acc[i][7] + be1.w};
    *(float4*)(P + o) = o0;
    *(float4*)(P + o + 4) = o1;
  }
}

// ---------------- TopK: exact radix-select, conflict-free, atomic-light ----------
#define SCAN256()                                            \
  do {                                                       \
    for (int off = 1; off < 256; off <<= 1) {                \
      unsigned v = scan[tid];                                \
      unsigned a = (tid >= off) ? scan[tid - off] : 0u;      \
      __syncthreads();                                       \
      scan[tid] = v + a;                                     \
      __syncthreads();                                       \
    }                                                        \
  } while (0)

__global__ __launch_bounds__(256) void k_topk(
    float* __restrict__ H, float* __restrict__ sel_v, int* __restrict__ sel_i) {
  __shared__ float row[D_HID];          // 64KB
  __shared__ unsigned hist[4][256];     // per-wave replicas
  __shared__ unsigned scan[256];
  __shared__ unsigned sh_prefix, sh_cntgt;
  __shared__ int eqbuf[256];
  __shared__ unsigned eqn, keepn;
  __shared__ int sh_eqcut;
  const int tid = threadIdx.x;
  const size_t t = blockIdx.x;
  float* rowg = H + t * D_HID;

  for (int i = tid; i < D_HID / 4; i += 256) {
    float4 v = ((const float4*)rowg)[i];
    v.x = v.x > 0.f ? v.x : 0.f;
    v.y = v.y > 0.f ? v.y : 0.f;
    v.z = v.z > 0.f ? v.z : 0.f;
    v.w = v.w > 0.f ? v.w : 0.f;
    ((float4*)row)[i] = v;
  }
  if (tid == 0) { sh_prefix = 0; sh_cntgt = 0; eqn = 0; keepn = 0; }
  __syncthreads();

  const f32x4* row4 = (const f32x4*)row;
  for (int p = 3; p >= 0; p--) {
    hist[0][tid] = 0; hist[1][tid] = 0; hist[2][tid] = 0; hist[3][tid] = 0;
    __syncthreads();
    const unsigned prefix = sh_prefix;
    const unsigned need = KSEL - sh_cntgt;
    const unsigned hi_mask = (p == 3) ? 0u : (0xFFFFFFFFu << (8 * (p + 1)));
    const int sh = 8 * p;
    unsigned* hrep = hist[tid >> 6];
    for (int j = 0; j < D_HID / 1024; j++) {       // 16 x f32x4 per thread
      f32x4 v = row4[j * 256 + tid];
#pragma unroll
      for (int e = 0; e < 4; e++) {
        unsigned bits = __float_as_uint(v[e]);
        if (bits && ((bits ^ prefix) & hi_mask) == 0)
          atomicAdd(&hrep[(bits >> sh) & 255], 1u);
      }
    }
    __syncthreads();
    scan[tid] = hist[0][255 - tid] + hist[1][255 - tid] + hist[2][255 - tid] + hist[3][255 - tid];
    __syncthreads();
    SCAN256();
    unsigned Sb  = scan[255 - tid];
    unsigned Sb1 = (tid == 255) ? 0u : scan[254 - tid];
    if (Sb >= need && Sb1 < need) {
      sh_prefix = prefix | ((unsigned)tid << sh);
      sh_cntgt = (KSEL - need) + Sb1;
    }
    if (tid == 0 && scan[255] < need) {        // degenerate: zeros needed -> bin 0
      sh_prefix = prefix;
      sh_cntgt = (KSEL - need) + scan[255];
    }
    __syncthreads();
  }
  const unsigned thr = sh_prefix;
  const unsigned need_eq = KSEL - sh_cntgt;   // in [1, 64]

  // Phase A: find eqcut = need_eq-th smallest index with bits == thr.
  for (int j = 0; j < D_HID / 256; j++) {
    int idx = j * 256 + tid;
    if (__float_as_uint(row[idx]) == thr) {
      unsigned p = atomicAdd(&eqn, 1u);
      if (p < 256) eqbuf[p] = idx;
    }
  }
  __syncthreads();
  const unsigned en = eqn;
  if (en <= 256) {
    if (tid < en) {
      int mine = eqbuf[tid];
      unsigned rank = 0;
      for (unsigned j = 0; j < en; j++) rank += (eqbuf[j] < mine) ? 1u : 0u;
      if (rank == need_eq - 1) sh_eqcut = mine;
    }
    __syncthreads();
  } else {
    int lo = 0, hi = D_HID - 1;
    while (lo < hi) {
      int mid = (lo + hi) >> 1;
      if (tid == 0) scan[0] = 0;
      __syncthreads();
      unsigned c = 0;
      for (int j = 0; j < D_HID / 256; j++) {
        int idx = j * 256 + tid;
        if (idx <= mid && __float_as_uint(row[idx]) == thr) c++;
      }
      atomicAdd(&scan[0], c);
      __syncthreads();
      if (scan[0] >= need_eq) hi = mid; else lo = mid + 1;
      __syncthreads();
    }
    if (tid == 0) sh_eqcut = lo;
    __syncthreads();
  }
  const int eqcut = sh_eqcut;

  // Phase B+C merged: mask + write sparse row; append kept (idx,val) to sel
  for (int i = tid; i < D_HID / 4; i += 256) {
    f32x4 v = ((const f32x4*)row)[i];
    int i0 = i * 4;
#pragma unroll
    for (int e = 0; e < 4; e++) {
      unsigned b = __float_as_uint(v[e]);
      bool keep = (b > thr) || (b == thr && i0 + e <= eqcut);
      if (keep) {
        unsigned p = atomicAdd(&keepn, 1u);
        sel_v[t * KSEL + p] = v[e];
        sel_i[t * KSEL + p] = i0 + e;
      } else {
        v[e] = 0.f;
      }
    }
    __builtin_nontemporal_store(v, (f32x4*)rowg + i);
  }
}

// ---------------- W_dec transpose -> f16 (64x64 tile, 128-B write segments) ------
__global__ __launch_bounds__(256) void k_transpose(const float* __restrict__ in,
                                                   f16* __restrict__ out) {
  __shared__ float tile[64][65];
  const int bx = blockIdx.x;   // h tiles (D_HID/64)
  const int by = blockIdx.y;   // d tiles (D_IN/64)
  const int tid = threadIdx.x;
#pragma unroll
  for (int p = 0; p < 16; p++) {
    int lin = p * 256 + tid;
    int dr = lin >> 6;          // d offset 0..63
    int dc = lin & 63;          // h offset 0..63
    tile[dc][dr] = in[(size_t)(by * 64 + dr) * D_HID + bx * 64 + dc];
  }
  __syncthreads();
#pragma unroll
  for (int p = 0; p < 16; p++) {
    int lin = p * 256 + tid;
    int h = lin >> 6;           // h offset 0..63
    int d = lin & 63;           // d offset 0..63
    out[(size_t)(bx * 64 + h) * D_IN + by * 64 + d] = (f16)tile[h][d];
  }
}

// ---------------- Decoder: z_rec[t,:] = sum_k val_k * WdT[idx_k,:] + b_dec -------
__global__ __launch_bounds__(512) void k_decode(
    const float* __restrict__ sel_v, const int* __restrict__ sel_i,
    const f16* __restrict__ WdT, const float* __restrict__ b_dec,
    float* __restrict__ out) {
  const int tid = threadIdx.x;
  const size_t t = blockIdx.x;
  __shared__ float sv[KSEL];
  __shared__ int si[KSEL];
  if (tid < KSEL) { sv[tid] = sel_v[t * KSEL + tid]; si[tid] = sel_i[t * KSEL + tid]; }
  __syncthreads();
  float acc[8];
#pragma unroll
  for (int e = 0; e < 8; e++) acc[e] = b_dec[tid * 8 + e];
#pragma unroll 8
  for (int k = 0; k < KSEL; k++) {
    float v = sv[k];
    f16x8 w = ((const f16x8*)(WdT + (size_t)si[k] * D_IN))[tid];
#pragma unroll
    for (int e = 0; e < 8; e++) acc[e] += v * (float)w[e];
  }
  const int d0 = tid * 8;
  f32x4 o0 = {acc[0], acc[1], acc[2], acc[3]};
  f32x4 o1 = {acc[4], acc[5], acc[6], acc[7]};
  __builtin_nontemporal_store(o0, (f32x4*)(out + t * D_IN + d0));
  __builtin_nontemporal_store(o1, (f32x4*)(out + t * D_IN + d0 + 4));
  int l = d0 >> 10, off = d0 & 1023;
  float* lp = out + OUT_LAYER + ((size_t)l * NTOK + t) * 1024 + off;
  __builtin_nontemporal_store(o0, (f32x4*)lp);
  __builtin_nontemporal_store(o1, (f32x4*)(lp + 4));
}

// Fallback decoder without transposed W_dec (slow but correct)
__global__ __launch_bounds__(256) void k_decode_slow(
    const float* __restrict__ sel_v, const int* __restrict__ sel_i,
    const float* __restrict__ Wd, const float* __restrict__ b_dec,
    float* __restrict__ out) {
  const int tid = threadIdx.x;
  const size_t t = blockIdx.x;
  __shared__ float sv[KSEL];
  __shared__ int si[KSEL];
  if (tid < KSEL) { sv[tid] = sel_v[t * KSEL + tid]; si[tid] = sel_i[t * KSEL + tid]; }
  __syncthreads();
  float acc[16];
#pragma unroll
  for (int i = 0; i < 16; i++) acc[i] = b_dec[i * 256 + tid];
  for (int k = 0; k < KSEL; k++) {
    float v = sv[k];
    int idx = si[k];
#pragma unroll
    for (int i = 0; i < 16; i++)
      acc[i] += v * Wd[(size_t)(i * 256 + tid) * D_HID + idx];
  }
  for (int i = 0; i < 16; i++) {
    int d = i * 256 + tid;
    out[t * D_IN + d] = acc[i];
    int l = d >> 10, off = d & 1023;
    out[OUT_LAYER + (size_t)l * NTOK * 1024 + t * 1024 + off] = acc[i];
  }
}

extern "C" void kernel_launch(void* const* d_in, const int* in_sizes, int n_in,
                              void* d_out, int out_size, void* d_ws, size_t ws_size,
                              hipStream_t stream) {
  const float* z     = (const float*)d_in[0];
  const float* W_enc = (const float*)d_in[1];
  const float* b_enc = (const float*)d_in[2];
  const float* W_dec = (const float*)d_in[3];
  const float* b_dec = (const float*)d_in[4];
  float* out = (float*)d_out;
  float* pre = out + OUT_H;  // pre-activations live in the h_sparse output slot

  float* sel_v = (float*)d_ws;                              // 1 MiB
  int*   sel_i = (int*)((char*)d_ws + (1u << 20));          // 1 MiB
  char*  wsbig = (char*)d_ws + (2u << 20);                  // 256 MiB region
  const size_t need_ws = (size_t)(2u << 20) + (size_t)D_HID * D_IN * 4;
  const bool fast = ws_size >= need_ws;

  if (fast) {
    // A planes in the z_rec output region (dead until decode); W planes in the
    // ws region later overwritten by WdT (dead after GEMM).
    f16* Ahp = (f16*)out;                         // 32 MiB
    f16* Amp = Ahp + (size_t)NTOK * D_IN;         // 32 MiB
    f16* Whp = (f16*)wsbig;                       // 128 MiB
    f16* Wmp = Whp + (size_t)D_HID * D_IN;        // 128 MiB
    f16* WdT = (f16*)wsbig;                       // f16, reuses W-plane region after GEMM

    k_split_a<<<NTOK * D_IN / 1024, 256, 0, stream>>>(z, b_dec, Ahp, Amp);
    k_split_w<<<D_HID * D_IN / 1024, 256, 0, stream>>>(W_enc, Whp, Wmp);
    k_gemm3<<<(NTOK / BM) * (D_HID / BN), 512, 0, stream>>>(Ahp, Amp, Whp, Wmp, b_enc, pre);
    k_topk<<<NTOK, 256, 0, stream>>>(pre, sel_v, sel_i);
    k_transpose<<<dim3(D_HID / 64, D_IN / 64), 256, 0, stream>>>(W_dec, WdT);
    k_decode<<<NTOK, 512, 0, stream>>>(sel_v, sel_i, WdT, b_dec, out);
  } else {
    dim3 gb(D_HID / FBN, NTOK / FBM);
    k_gemm_enc<<<gb, 256, 0, stream>>>(z, W_enc, b_enc, b_dec, pre);
    k_topk<<<NTOK, 256, 0, stream>>>(pre, sel_v, sel_i);
    k_decode_slow<<<NTOK, 256, 0, stream>>>(sel_v, sel_i, W_dec, b_dec, out);
  }
}

// Round 16
// 1984.432 us; speedup vs baseline: 1.0622x; 1.0071x over previous
//
#include <hip/hip_runtime.h>

#define D_IN   4096      // D_CONCAT
#define D_HID  16384
#define NTOK   4096      // B*N
#define KSEL   64

// output layout (floats)
#define OUT_ZREC 0
#define OUT_H    ((size_t)NTOK * D_IN)                 // 16,777,216
#define OUT_LAYER (OUT_H + (size_t)NTOK * D_HID)       // 83,886,080

typedef _Float16 f16;
typedef _Float16 f16x4 __attribute__((ext_vector_type(4)));
typedef _Float16 f16x8 __attribute__((ext_vector_type(8)));
typedef float f32x4 __attribute__((ext_vector_type(4)));

#define GLOAD16(gp, lp) __builtin_amdgcn_global_load_lds( \
    (const __attribute__((address_space(1))) void*)(gp),  \
    (__attribute__((address_space(3))) void*)(lp), 16, 0, 0)

// ---------------- fp32 -> (hi,mid) f16 split kernels ----------------
__global__ __launch_bounds__(256) void k_split_a(
    const float* __restrict__ Z, const float* __restrict__ b_dec,
    f16* __restrict__ H, f16* __restrict__ M) {
  size_t i = (size_t)blockIdx.x * 256 + threadIdx.x;     // float4 index
  float4 x = ((const float4*)Z)[i];
  int col = (int)((i * 4) & (D_IN - 1));
  float4 b = *(const float4*)(b_dec + col);
  x.x -= b.x; x.y -= b.y; x.z -= b.z; x.w -= b.w;
  f16 h0 = (f16)x.x, h1 = (f16)x.y, h2 = (f16)x.z, h3 = (f16)x.w;
  f16 m0 = (f16)(x.x - (float)h0), m1 = (f16)(x.y - (float)h1);
  f16 m2 = (f16)(x.z - (float)h2), m3 = (f16)(x.w - (float)h3);
  f16x4 hv = {h0, h1, h2, h3}, mv = {m0, m1, m2, m3};
  ((f16x4*)H)[i] = hv;
  ((f16x4*)M)[i] = mv;
}

__global__ __launch_bounds__(256) void k_split_w(
    const float* __restrict__ W, f16* __restrict__ H, f16* __restrict__ M) {
  size_t i = (size_t)blockIdx.x * 256 + threadIdx.x;     // float4 index
  float4 x = ((const float4*)W)[i];
  f16 h0 = (f16)x.x, h1 = (f16)x.y, h2 = (f16)x.z, h3 = (f16)x.w;
  f16 m0 = (f16)(x.x - (float)h0), m1 = (f16)(x.y - (float)h1);
  f16 m2 = (f16)(x.z - (float)h2), m3 = (f16)(x.w - (float)h3);
  f16x4 hv = {h0, h1, h2, h3}, mv = {m0, m1, m2, m3};
  ((f16x4*)H)[i] = hv;
  ((f16x4*)M)[i] = mv;
}

// ---------------- split-f16 MFMA GEMM: pre = A @ W^T + b_enc ----------------
// R16: 256x256 tile, BK=32, **16 waves (4M x 4N, 1024 threads, 4 waves/SIMD)**,
// 128 KiB LDS double-buffer. Rationale: the 2-wave/SIMD config leaves the MFMA
// pipe idle at every barrier-aligned ds_read burst; 4 waves/SIMD gives the
// scheduler cover. acc[4][4] = 64 VGPR -> fits the 128-VGPR cap of
// __launch_bounds__(1024,4) without spill.
// MFMA shape: 16x16x32 ONLY. *** NUMERICS FROZEN (R9): per output element, K
// runs in 128 sequential BK=32 tiles, each adding hh -> hm -> mh. The wave->
// sub-tile map is spatial only — accumulation sequences are bit-identical. ***
// *** R12/R14 lessons: acc statically indexed; no duplicated unrolled MFMA
// bodies; spread (not burst) staging. ***
// LDS row = 128 B = 8 slots of 16 B; physical slot = g ^ (row & 7)  (T2 swizzle,
// pre-swizzled global source + swizzled ds_read; 0 conflicts, verified).
// Block mapping: bn-OUTER (L3-shared W window; R11: FETCH 2.1->1.6GB, +7% util).
#define BM 256
#define BN 256
#define BK 32
#define NT (D_IN / BK)   // 128

__global__ __launch_bounds__(1024, 4) void k_gemm3(
    const f16* __restrict__ Ahg, const f16* __restrict__ Amg,
    const f16* __restrict__ Whg, const f16* __restrict__ Wmg,
    const float* __restrict__ b_enc, float* __restrict__ P) {
  __shared__ __align__(16) char smem[131072];   // 2 buffers x 64 KiB
  const int tid = threadIdx.x;
  const int lane = tid & 63, w = tid >> 6;      // 16 waves

  const int bm = blockIdx.x & 15, bn = blockIdx.x >> 4;   // bn-outer (L3-shared W window)
  const int row0 = bm * BM, col0 = bn * BN;
  const int wr = w >> 2, wc = w & 3;     // 4 x 4 waves; wave tile 64 x 64

  // staging: 4 x 16B loads/thread per K-tile (2 A, 2 W), 1024 threads = 4096 loads
  const char* gp[4];
  int ldst[4];
#pragma unroll
  for (int j = 0; j < 4; j++) {
    int id = tid + j * 1024;
    bool isA = (j < 2);
    int r = isA ? (id >> 3) : ((id >> 3) - 256);   // 0..255
    int ps = id & 7;
    int g = ps ^ (r & 7);
    int plane = g >> 2, kc = g & 3;
    const f16* base = isA ? (plane ? Amg : Ahg) : (plane ? Wmg : Whg);
    int rg = (isA ? row0 : col0) + r;
    gp[j] = (const f16*)base ? (const char*)base + (size_t)rg * 8192 + kc * 16 : nullptr;
    ldst[j] = id * 16;                              // A: [0,32K), W: [32K,64K)
  }

  f32x4 acc[4][4] = {};
  const int l15 = lane & 15;
  const int physh = ((lane >> 4) ^ (lane & 7)) * 16;  // hi-plane slot byte
  const int physm = physh ^ 64;                       // mid-plane slot byte
  const int arow0 = wr * 64 + l15;
  const int wrow0 = wc * 64 + l15;

  // prologue: stage tile 0, publish
#pragma unroll
  for (int j = 0; j < 4; j++) { GLOAD16(gp[j], smem + ldst[j]); gp[j] += 64; }
  asm volatile("s_waitcnt vmcnt(0)" ::: "memory");
  __builtin_amdgcn_s_barrier();

  for (int t = 0; t < NT; t++) {
    const char* Ab = smem + (t & 1) * 65536;
    const char* Wb = Ab + 32768;
    const int nb = ((t + 1) & 1) * 65536;
    const bool pre = (t + 1 < NT);

    // stage load 0 early; loads 1..3 spread over the j-loop
    if (pre) { GLOAD16(gp[0], smem + nb + ldst[0]); gp[0] += 64; }

    f16x8 ah[4], am[4];
#pragma unroll
    for (int i = 0; i < 4; i++) {
      int ro = (arow0 + i * 16) * 128;
      ah[i] = *(const f16x8*)(Ab + ro + physh);
      am[i] = *(const f16x8*)(Ab + ro + physm);
    }
    __builtin_amdgcn_s_setprio(1);
#pragma unroll
    for (int j = 0; j < 4; j++) {
      if (j >= 1 && pre) { GLOAD16(gp[j], smem + nb + ldst[j]); gp[j] += 64; }
      int ro = (wrow0 + j * 16) * 128;
      f16x8 wh = *(const f16x8*)(Wb + ro + physh);
      f16x8 wm = *(const f16x8*)(Wb + ro + physm);
#pragma unroll
      for (int i = 0; i < 4; i++)
        acc[i][j] = __builtin_amdgcn_mfma_f32_16x16x32_f16(ah[i], wh, acc[i][j], 0, 0, 0);
#pragma unroll
      for (int i = 0; i < 4; i++)
        acc[i][j] = __builtin_amdgcn_mfma_f32_16x16x32_f16(ah[i], wm, acc[i][j], 0, 0, 0);
#pragma unroll
      for (int i = 0; i < 4; i++)
        acc[i][j] = __builtin_amdgcn_mfma_f32_16x16x32_f16(am[i], wh, acc[i][j], 0, 0, 0);
    }
    __builtin_amdgcn_s_setprio(0);
    asm volatile("s_waitcnt vmcnt(0)" ::: "memory");   // tile t+1 landed (issued 1 body ago)
    __builtin_amdgcn_sched_barrier(0);
    __builtin_amdgcn_s_barrier();
    __builtin_amdgcn_sched_barrier(0);
  }

  // epilogue: C/D layout col=lane&15, row=(lane>>4)*4+q (m89-verified)
  const int crow0 = row0 + wr * 64, ccol0 = col0 + wc * 64;
#pragma unroll
  for (int j = 0; j < 4; j++) {
    int col = ccol0 + j * 16 + l15;
    float be = b_enc[col];
#pragma unroll
    for (int i = 0; i < 4; i++) {
      int r = crow0 + i * 16 + ((lane >> 4) * 4);
#pragma unroll
      for (int q = 0; q < 4; q++)
        __builtin_nontemporal_store(acc[i][j][q] + be, P + (size_t)(r + q) * D_HID + col);
    }
  }
}

// ---------------- legacy fp32 GEMM (fallback when ws is too small) ----------------
#define FBM 128
#define FBN 128
#define FBK 32
__global__ __launch_bounds__(256) void k_gemm_enc(
    const float* __restrict__ Z, const float* __restrict__ W,
    const float* __restrict__ b_enc, const float* __restrict__ b_dec,
    float* __restrict__ P) {
  __shared__ float As[FBK][FBM + 4];
  __shared__ float Bs[FBK][FBN + 4];
  const int tid = threadIdx.x;
  const int bm = blockIdx.y, bn = blockIdx.x;
  const int ty = tid >> 4, tx = tid & 15;
  const int row0 = bm * FBM, col0 = bn * FBN;
  float acc[8][8];
#pragma unroll
  for (int i = 0; i < 8; i++)
#pragma unroll
    for (int j = 0; j < 8; j++) acc[i][j] = 0.f;
  for (int k0 = 0; k0 < D_IN; k0 += FBK) {
#pragma unroll
    for (int i = 0; i < 4; i++) {
      int f = tid + i * 256;
      int r = f >> 3;
      int c = (f & 7) * 4;
      float4 bd = *(const float4*)(b_dec + k0 + c);
      float4 a = *(const float4*)(Z + (size_t)(row0 + r) * D_IN + k0 + c);
      float4 w = *(const float4*)(W + (size_t)(col0 + r) * D_IN + k0 + c);
      As[c + 0][r] = a.x - bd.x; As[c + 1][r] = a.y - bd.y;
      As[c + 2][r] = a.z - bd.z; As[c + 3][r] = a.w - bd.w;
      Bs[c + 0][r] = w.x; Bs[c + 1][r] = w.y;
      Bs[c + 2][r] = w.z; Bs[c + 3][r] = w.w;
    }
    __syncthreads();
#pragma unroll
    for (int kk = 0; kk < FBK; kk++) {
      const float4* ap = (const float4*)&As[kk][ty * 8];
      const float4* bp = (const float4*)&Bs[kk][tx * 8];
      float4 a0 = ap[0], a1 = ap[1], b0 = bp[0], b1 = bp[1];
      float a[8] = {a0.x, a0.y, a0.z, a0.w, a1.x, a1.y, a1.z, a1.w};
      float b[8] = {b0.x, b0.y, b0.z, b0.w, b1.x, b1.y, b1.z, b1.w};
#pragma unroll
      for (int i = 0; i < 8; i++)
#pragma unroll
        for (int j = 0; j < 8; j++) acc[i][j] += a[i] * b[j];
    }
    __syncthreads();
  }
  float4 be0 = *(const float4*)(b_enc + col0 + tx * 8);
  float4 be1 = *(const float4*)(b_enc + col0 + tx * 8 + 4);
#pragma unroll
  for (int i = 0; i < 8; i++) {
    size_t o = (size_t)(row0 + ty * 8 + i) * D_HID + col0 + tx * 8;
    float4 o0 = {acc[i][0] + be0.x, acc[i][1] + be0.y, acc[i][2] + be0.z, acc[i][3] + be0.w};
    float4 o1 = {acc[i][4] + be1.x, acc[i][5] + be1.y, acc[i][6] + be1.z, acc[i][7] + be1.w};
    *(float4*)(P + o) = o0;
    *(float4*)(P + o + 4) = o1;
  }
}

// ---------------- TopK: exact radix-select, conflict-free, atomic-light ----------
#define SCAN256()                                            \
  do {                                                       \
    for (int off = 1; off < 256; off <<= 1) {                \
      unsigned v = scan[tid];                                \
      unsigned a = (tid >= off) ? scan[tid - off] : 0u;      \
      __syncthreads();                                       \
      scan[tid] = v + a;                                     \
      __syncthreads();                                       \
    }                                                        \
  } while (0)

__global__ __launch_bounds__(256) void k_topk(
    float* __restrict__ H, float* __restrict__ sel_v, int* __restrict__ sel_i) {
  __shared__ float row[D_HID];          // 64KB
  __shared__ unsigned hist[4][256];     // per-wave replicas
  __shared__ unsigned scan[256];
  __shared__ unsigned sh_prefix, sh_cntgt;
  __shared__ int eqbuf[256];
  __shared__ unsigned eqn, keepn;
  __shared__ int sh_eqcut;
  const int tid = threadIdx.x;
  const size_t t = blockIdx.x;
  float* rowg = H + t * D_HID;

  for (int i = tid; i < D_HID / 4; i += 256) {
    float4 v = ((const float4*)rowg)[i];
    v.x = v.x > 0.f ? v.x : 0.f;
    v.y = v.y > 0.f ? v.y : 0.f;
    v.z = v.z > 0.f ? v.z : 0.f;
    v.w = v.w > 0.f ? v.w : 0.f;
    ((float4*)row)[i] = v;
  }
  if (tid == 0) { sh_prefix = 0; sh_cntgt = 0; eqn = 0; keepn = 0; }
  __syncthreads();

  const f32x4* row4 = (const f32x4*)row;
  for (int p = 3; p >= 0; p--) {
    hist[0][tid] = 0; hist[1][tid] = 0; hist[2][tid] = 0; hist[3][tid] = 0;
    __syncthreads();
    const unsigned prefix = sh_prefix;
    const unsigned need = KSEL - sh_cntgt;
    const unsigned hi_mask = (p == 3) ? 0u : (0xFFFFFFFFu << (8 * (p + 1)));
    const int sh = 8 * p;
    unsigned* hrep = hist[tid >> 6];
    for (int j = 0; j < D_HID / 1024; j++) {       // 16 x f32x4 per thread
      f32x4 v = row4[j * 256 + tid];
#pragma unroll
      for (int e = 0; e < 4; e++) {
        unsigned bits = __float_as_uint(v[e]);
        if (bits && ((bits ^ prefix) & hi_mask) == 0)
          atomicAdd(&hrep[(bits >> sh) & 255], 1u);
      }
    }
    __syncthreads();
    scan[tid] = hist[0][255 - tid] + hist[1][255 - tid] + hist[2][255 - tid] + hist[3][255 - tid];
    __syncthreads();
    SCAN256();
    unsigned Sb  = scan[255 - tid];
    unsigned Sb1 = (tid == 255) ? 0u : scan[254 - tid];
    if (Sb >= need && Sb1 < need) {
      sh_prefix = prefix | ((unsigned)tid << sh);
      sh_cntgt = (KSEL - need) + Sb1;
    }
    if (tid == 0 && scan[255] < need) {        // degenerate: zeros needed -> bin 0
      sh_prefix = prefix;
      sh_cntgt = (KSEL - need) + scan[255];
    }
    __syncthreads();
  }
  const unsigned thr = sh_prefix;
  const unsigned need_eq = KSEL - sh_cntgt;   // in [1, 64]

  // Phase A: find eqcut = need_eq-th smallest index with bits == thr.
  for (int j = 0; j < D_HID / 256; j++) {
    int idx = j * 256 + tid;
    if (__float_as_uint(row[idx]) == thr) {
      unsigned p = atomicAdd(&eqn, 1u);
      if (p < 256) eqbuf[p] = idx;
    }
  }
  __syncthreads();
  const unsigned en = eqn;
  if (en <= 256) {
    if (tid < en) {
      int mine = eqbuf[tid];
      unsigned rank = 0;
      for (unsigned j = 0; j < en; j++) rank += (eqbuf[j] < mine) ? 1u : 0u;
      if (rank == need_eq - 1) sh_eqcut = mine;
    }
    __syncthreads();
  } else {
    int lo = 0, hi = D_HID - 1;
    while (lo < hi) {
      int mid = (lo + hi) >> 1;
      if (tid == 0) scan[0] = 0;
      __syncthreads();
      unsigned c = 0;
      for (int j = 0; j < D_HID / 256; j++) {
        int idx = j * 256 + tid;
        if (idx <= mid && __float_as_uint(row[idx]) == thr) c++;
      }
      atomicAdd(&scan[0], c);
      __syncthreads();
      if (scan[0] >= need_eq) hi = mid; else lo = mid + 1;
      __syncthreads();
    }
    if (tid == 0) sh_eqcut = lo;
    __syncthreads();
  }
  const int eqcut = sh_eqcut;

  // Phase B+C merged: mask + write sparse row; append kept (idx,val) to sel
  for (int i = tid; i < D_HID / 4; i += 256) {
    f32x4 v = ((const f32x4*)row)[i];
    int i0 = i * 4;
#pragma unroll
    for (int e = 0; e < 4; e++) {
      unsigned b = __float_as_uint(v[e]);
      bool keep = (b > thr) || (b == thr && i0 + e <= eqcut);
      if (keep) {
        unsigned p = atomicAdd(&keepn, 1u);
        sel_v[t * KSEL + p] = v[e];
        sel_i[t * KSEL + p] = i0 + e;
      } else {
        v[e] = 0.f;
      }
    }
    __builtin_nontemporal_store(v, (f32x4*)rowg + i);
  }
}

// ---------------- W_dec transpose -> f16 (64x64 tile, 128-B write segments) ------
__global__ __launch_bounds__(256) void k_transpose(const float* __restrict__ in,
                                                   f16* __restrict__ out) {
  __shared__ float tile[64][65];
  const int bx = blockIdx.x;   // h tiles (D_HID/64)
  const int by = blockIdx.y;   // d tiles (D_IN/64)
  const int tid = threadIdx.x;
#pragma unroll
  for (int p = 0; p < 16; p++) {
    int lin = p * 256 + tid;
    int dr = lin >> 6;          // d offset 0..63
    int dc = lin & 63;          // h offset 0..63
    tile[dc][dr] = in[(size_t)(by * 64 + dr) * D_HID + bx * 64 + dc];
  }
  __syncthreads();
#pragma unroll
  for (int p = 0; p < 16; p++) {
    int lin = p * 256 + tid;
    int h = lin >> 6;           // h offset 0..63
    int d = lin & 63;           // d offset 0..63
    out[(size_t)(bx * 64 + h) * D_IN + by * 64 + d] = (f16)tile[h][d];
  }
}

// ---------------- Decoder: z_rec[t,:] = sum_k val_k * WdT[idx_k,:] + b_dec -------
__global__ __launch_bounds__(512) void k_decode(
    const float* __restrict__ sel_v, const int* __restrict__ sel_i,
    const f16* __restrict__ WdT, const float* __restrict__ b_dec,
    float* __restrict__ out) {
  const int tid = threadIdx.x;
  const size_t t = blockIdx.x;
  __shared__ float sv[KSEL];
  __shared__ int si[KSEL];
  if (tid < KSEL) { sv[tid] = sel_v[t * KSEL + tid]; si[tid] = sel_i[t * KSEL + tid]; }
  __syncthreads();
  float acc[8];
#pragma unroll
  for (int e = 0; e < 8; e++) acc[e] = b_dec[tid * 8 + e];
#pragma unroll 8
  for (int k = 0; k < KSEL; k++) {
    float v = sv[k];
    f16x8 w = ((const f16x8*)(WdT + (size_t)si[k] * D_IN))[tid];
#pragma unroll
    for (int e = 0; e < 8; e++) acc[e] += v * (float)w[e];
  }
  const int d0 = tid * 8;
  f32x4 o0 = {acc[0], acc[1], acc[2], acc[3]};
  f32x4 o1 = {acc[4], acc[5], acc[6], acc[7]};
  __builtin_nontemporal_store(o0, (f32x4*)(out + t * D_IN + d0));
  __builtin_nontemporal_store(o1, (f32x4*)(out + t * D_IN + d0 + 4));
  int l = d0 >> 10, off = d0 & 1023;
  float* lp = out + OUT_LAYER + ((size_t)l * NTOK + t) * 1024 + off;
  __builtin_nontemporal_store(o0, (f32x4*)lp);
  __builtin_nontemporal_store(o1, (f32x4*)(lp + 4));
}

// Fallback decoder without transposed W_dec (slow but correct)
__global__ __launch_bounds__(256) void k_decode_slow(
    const float* __restrict__ sel_v, const int* __restrict__ sel_i,
    const float* __restrict__ Wd, const float* __restrict__ b_dec,
    float* __restrict__ out) {
  const int tid = threadIdx.x;
  const size_t t = blockIdx.x;
  __shared__ float sv[KSEL];
  __shared__ int si[KSEL];
  if (tid < KSEL) { sv[tid] = sel_v[t * KSEL + tid]; si[tid] = sel_i[t * KSEL + tid]; }
  __syncthreads();
  float acc[16];
#pragma unroll
  for (int i = 0; i < 16; i++) acc[i] = b_dec[i * 256 + tid];
  for (int k = 0; k < KSEL; k++) {
    float v = sv[k];
    int idx = si[k];
#pragma unroll
    for (int i = 0; i < 16; i++)
      acc[i] += v * Wd[(size_t)(i * 256 + tid) * D_HID + idx];
  }
  for (int i = 0; i < 16; i++) {
    int d = i * 256 + tid;
    out[t * D_IN + d] = acc[i];
    int l = d >> 10, off = d & 1023;
    out[OUT_LAYER + (size_t)l * NTOK * 1024 + t * 1024 + off] = acc[i];
  }
}

extern "C" void kernel_launch(void* const* d_in, const int* in_sizes, int n_in,
                              void* d_out, int out_size, void* d_ws, size_t ws_size,
                              hipStream_t stream) {
  const float* z     = (const float*)d_in[0];
  const float* W_enc = (const float*)d_in[1];
  const float* b_enc = (const float*)d_in[2];
  const float* W_dec = (const float*)d_in[3];
  const float* b_dec = (const float*)d_in[4];
  float* out = (float*)d_out;
  float* pre = out + OUT_H;  // pre-activations live in the h_sparse output slot

  float* sel_v = (float*)d_ws;                              // 1 MiB
  int*   sel_i = (int*)((char*)d_ws + (1u << 20));          // 1 MiB
  char*  wsbig = (char*)d_ws + (2u << 20);                  // 256 MiB region
  const size_t need_ws = (size_t)(2u << 20) + (size_t)D_HID * D_IN * 4;
  const bool fast = ws_size >= need_ws;

  if (fast) {
    // A planes in the z_rec output region (dead until decode); W planes in the
    // ws region later overwritten by WdT (dead after GEMM).
    f16* Ahp = (f16*)out;                         // 32 MiB
    f16* Amp = Ahp + (size_t)NTOK * D_IN;         // 32 MiB
    f16* Whp = (f16*)wsbig;                       // 128 MiB
    f16* Wmp = Whp + (size_t)D_HID * D_IN;        // 128 MiB
    f16* WdT = (f16*)wsbig;                       // f16, reuses W-plane region after GEMM

    k_split_a<<<NTOK * D_IN / 1024, 256, 0, stream>>>(z, b_dec, Ahp, Amp);
    k_split_w<<<D_HID * D_IN / 1024, 256, 0, stream>>>(W_enc, Whp, Wmp);
    k_gemm3<<<(NTOK / BM) * (D_HID / BN), 1024, 0, stream>>>(Ahp, Amp, Whp, Wmp, b_enc, pre);
    k_topk<<<NTOK, 256, 0, stream>>>(pre, sel_v, sel_i);
    k_transpose<<<dim3(D_HID / 64, D_IN / 64), 256, 0, stream>>>(W_dec, WdT);
    k_decode<<<NTOK, 512, 0, stream>>>(sel_v, sel_i, WdT, b_dec, out);
  } else {
    dim3 gb(D_HID / FBN, NTOK / FBM);
    k_gemm_enc<<<gb, 256, 0, stream>>>(z, W_enc, b_enc, b_dec, pre);
    k_topk<<<NTOK, 256, 0, stream>>>(pre, sel_v, sel_i);
    k_decode_slow<<<NTOK, 256, 0, stream>>>(sel_v, sel_i, W_dec, b_dec, out);
  }
}